// Round 2
// baseline (9736.995 us; speedup 1.0000x reference)
//
#include <hip/hip_runtime.h>
#include <hip/hip_cooperative_groups.h>

// x: [B=256, T=100, D=4096] f32; Z: [H=1024, D=4096] f32; KFinv: [D, H] f32
// out[:,t,:] = sigmoid((x_t - nb_{t-1}) @ KFinv + b_h) @ Z + b_out), nb_{-1}=b_out
#define T_SEQ 100
#define DD 4096
#define HH 1024
#define BB 256

#define GRID_WG 256   // == CU count: cooperative launch safe at 1 block/CU
#define BLOCK_T 512   // 8 waves

typedef __attribute__((ext_vector_type(8))) short short8;
typedef __attribute__((ext_vector_type(4))) float float4_t;

__device__ __forceinline__ short f2bf(float f) {
  union { float f; unsigned u; } v; v.f = f;
  unsigned r = v.u + 0x7fffu + ((v.u >> 16) & 1u);  // RNE
  return (short)(r >> 16);
}

// one-time prep: f32 [K][N] -> bf16 [N][K]
__global__ __launch_bounds__(256) void transpose_cvt(const float* __restrict__ src,
                                                     short* __restrict__ dst,
                                                     int K, int N) {
  __shared__ float tile[32][33];
  int k0 = blockIdx.x * 32, n0 = blockIdx.y * 32;
  int tx = threadIdx.x & 31, ty = threadIdx.x >> 5;  // 32 x 8
#pragma unroll
  for (int i = 0; i < 32; i += 8)
    tile[ty + i][tx] = src[(size_t)(k0 + ty + i) * N + n0 + tx];
  __syncthreads();
#pragma unroll
  for (int i = 0; i < 32; i += 8)
    dst[(size_t)(n0 + ty + i) * K + k0 + tx] = f2bf(tile[tx][ty + i]);
}

__global__ __launch_bounds__(BLOCK_T, 2) void gru_persist(
    const float* __restrict__ x, const short* __restrict__ KFt /*[H][D] bf16*/,
    const short* __restrict__ Zt /*[D][H] bf16*/, const float* __restrict__ b_out,
    const float* __restrict__ b_hidden, short* __restrict__ diff /*[B][D] bf16*/,
    float* __restrict__ hb /*[B][H] f32*/, float* __restrict__ out) {
  __shared__ short smem[2][8704];  // 2 x 17408 B
  auto grid = cooperative_groups::this_grid();

  const int g = blockIdx.x, tid = threadIdx.x;
  const int lane = tid & 63, wid = tid >> 6;
  const int quad = lane >> 4, l15 = lane & 15;
  const int gsize = GRID_WG * BLOCK_T;
  const int gtid = g * BLOCK_T + tid;

  // ---- init: diff_0 = x[:,0,:] - b_out (exact: x binary, b_out zeros)
  for (int idx = gtid; idx < BB * DD; idx += gsize) {
    int m = idx >> 12, d = idx & (DD - 1);
    diff[idx] = f2bf(x[(size_t)m * T_SEQ * DD + d] - b_out[d]);
  }
  grid.sync();

  // Phase A mapping: XCD x handles nA slices {4x..4x+3}; 8 m-tiles x 4 n per XCD.
  const int xcd = g & 7, loc = g >> 3;
  const int maA = (loc & 7) * 32;               // m base (tile 32)
  const int naA = (4 * xcd + (loc >> 3)) * 32;  // n base (tile 32)
  const int wkA = wid >> 2, wqA = wid & 3;      // 2 k-halves x 4 quadrant waves
  const int wmA = wqA >> 1, wnA = wqA & 1;
  // Phase B mapping: XCD x handles nB slices {8x..8x+7}; 4 m-tiles x 8 n per XCD.
  const int maB = (loc & 3) * 64;               // m base (tile 64)
  const int naB = (8 * xcd + (loc >> 2)) * 64;  // n base (tile 64)
  const int wmB = wid >> 1, wnB = wid & 1;      // 4 x 2 waves over 64x64
  // staging coords
  const int srA = tid >> 4, scA = tid & 15;  // 32 rows x 16 chunks(16 shorts)
  const int srB = tid >> 3, scB = tid & 7;   // 64 rows x 8 chunks(16 elems)

  for (int t = 0; t < T_SEQ; ++t) {
    // ============ Phase A: hb = diff @ KFinv + b_hidden  (tile 32x32, K=4096)
    {
      float4_t acc = {0.f, 0.f, 0.f, 0.f};
      short* sA = smem[0];  // 32 rows, pitch 264 shorts
      short* sB = smem[1];
#pragma unroll 1
      for (int it = 0; it < 16; ++it) {  // K chunks of 256
        const int kb = it * 256;
        const short* gp = &diff[(size_t)(maA + srA) * DD + kb + scA * 16];
        short8 v0 = *(const short8*)gp;
        short8 v1 = *(const short8*)(gp + 8);
        const short* gq = &KFt[(size_t)(naA + srA) * DD + kb + scA * 16];
        short8 u0 = *(const short8*)gq;
        short8 u1 = *(const short8*)(gq + 8);
        *(short8*)&sA[srA * 264 + scA * 16] = v0;
        *(short8*)&sA[srA * 264 + scA * 16 + 8] = v1;
        *(short8*)&sB[srA * 264 + scA * 16] = u0;
        *(short8*)&sB[srA * 264 + scA * 16 + 8] = u1;
        __syncthreads();
        const int ko = wkA * 128;
#pragma unroll
        for (int ks = 0; ks < 4; ++ks) {
          short8 a = *(const short8*)&sA[(wmA * 16 + l15) * 264 + ko + ks * 32 + quad * 8];
          short8 b = *(const short8*)&sB[(wnA * 16 + l15) * 264 + ko + ks * 32 + quad * 8];
          acc = __builtin_amdgcn_mfma_f32_16x16x32_bf16(a, b, acc, 0, 0, 0);
        }
        __syncthreads();
      }
      // cross-k-half reduce through LDS, then exclusive-owner store
      float* red = (float*)smem[0];
      if (wkA == 1) {
#pragma unroll
        for (int r = 0; r < 4; ++r) red[(wqA * 64 + lane) * 4 + r] = acc[r];
      }
      __syncthreads();
      if (wkA == 0) {
#pragma unroll
        for (int r = 0; r < 4; ++r) {
          float v = acc[r] + red[(wqA * 64 + lane) * 4 + r];
          int m = maA + wmA * 16 + quad * 4 + r;
          int n = naA + wnA * 16 + l15;
          hb[m * HH + n] = v + b_hidden[n];
        }
      }
    }
    grid.sync();

    // ============ Phase B: s = sigmoid(hb @ Z + b_out); out, diff_{t+1} =====
    {
      float4_t acc2[2] = {};
#pragma unroll 1
      for (int it = 0; it < 8; ++it) {  // K chunks of 128 (K=1024)
        const int kb = it * 128;
        const float* hp = &hb[(maB + srB) * HH + kb + scB * 16];
        short8 v0, v1;
#pragma unroll
        for (int j = 0; j < 8; ++j) v0[j] = f2bf(hp[j]);
#pragma unroll
        for (int j = 0; j < 8; ++j) v1[j] = f2bf(hp[8 + j]);
        const short* gq = &Zt[(size_t)(naB + srB) * HH + kb + scB * 16];
        short8 u0 = *(const short8*)gq;
        short8 u1 = *(const short8*)(gq + 8);
        *(short8*)&smem[0][srB * 136 + scB * 16] = v0;
        *(short8*)&smem[0][srB * 136 + scB * 16 + 8] = v1;
        *(short8*)&smem[1][srB * 136 + scB * 16] = u0;
        *(short8*)&smem[1][srB * 136 + scB * 16 + 8] = u1;
        __syncthreads();
#pragma unroll
        for (int ks = 0; ks < 4; ++ks) {
          short8 a  = *(const short8*)&smem[0][(wmB * 16 + l15) * 136 + ks * 32 + quad * 8];
          short8 b0 = *(const short8*)&smem[1][(wnB * 32 + l15) * 136 + ks * 32 + quad * 8];
          short8 b1 = *(const short8*)&smem[1][(wnB * 32 + 16 + l15) * 136 + ks * 32 + quad * 8];
          acc2[0] = __builtin_amdgcn_mfma_f32_16x16x32_bf16(a, b0, acc2[0], 0, 0, 0);
          acc2[1] = __builtin_amdgcn_mfma_f32_16x16x32_bf16(a, b1, acc2[1], 0, 0, 0);
        }
        __syncthreads();
      }
#pragma unroll
      for (int f = 0; f < 2; ++f)
#pragma unroll
        for (int r = 0; r < 4; ++r) {
          int m = maB + wmB * 16 + quad * 4 + r;
          int n = naB + wnB * 32 + f * 16 + l15;
          float z = acc2[f][r] + b_out[n];
          float s = 1.f / (1.f + __expf(-z));
          out[((size_t)m * T_SEQ + t) * DD + n] = s;
          if (t < T_SEQ - 1)
            diff[(size_t)m * DD + n] = f2bf(x[((size_t)m * T_SEQ + t + 1) * DD + n] - s);
        }
    }
    grid.sync();
  }
}

extern "C" void kernel_launch(void* const* d_in, const int* in_sizes, int n_in,
                              void* d_out, int out_size, void* d_ws, size_t ws_size,
                              hipStream_t stream) {
  const float* x = (const float*)d_in[0];
  const float* Z = (const float*)d_in[1];
  const float* b_out = (const float*)d_in[2];
  const float* KFinv = (const float*)d_in[3];
  const float* b_hidden = (const float*)d_in[4];
  float* out = (float*)d_out;

  char* ws = (char*)d_ws;
  short* KFt = (short*)ws;                 // [1024][4096] bf16 : 8 MiB
  short* Zt = (short*)(ws + 8388608);      // [4096][1024] bf16 : 8 MiB
  short* diff = (short*)(ws + 16777216);   // [256][4096] bf16  : 2 MiB
  float* hb = (float*)(ws + 18874368);     // [256][1024] f32   : 1 MiB

  transpose_cvt<<<dim3(128, 32), 256, 0, stream>>>(KFinv, KFt, 4096, 1024);
  transpose_cvt<<<dim3(32, 128), 256, 0, stream>>>(Z, Zt, 1024, 4096);

  void* args[] = {(void*)&x,        (void*)&KFt,  (void*)&Zt, (void*)&b_out,
                  (void*)&b_hidden, (void*)&diff, (void*)&hb, (void*)&out};
  hipLaunchCooperativeKernel((void*)gru_persist, dim3(GRID_WG), dim3(BLOCK_T), args, 0,
                             stream);
}